// Round 12
// baseline (287.293 us; speedup 1.0000x reference)
//
#include <hip/hip_runtime.h>
#include <hip/hip_bf16.h>

#define NNODE 1024
#define DIM 128
#define HEADS 8
#define DK 16
#define EDIM 16
#define BN 8               // target nodes per attn block
#define NGRP 8             // m-group blocks per target row (128 rows each)
#define LOG2E 1.44269504f

// per-WAVE region (dwords), UNPADDED (global_load_lds writes linearly;
// conflict-freedom via source-swizzle + rotated read, verified r7/r8:
// bank conflicts 1.83M -> 254K):
//   kv parity p (0,1) at wid*WREG + p*512:
//     k [2 rows][128] at +0   (LDS slot s holds global d-slot (s-(h>>1))&3)
//     v [2 rows][128] at +256
//   ef buffer b (0..3) at wid*WREG + 1024 + b*256:  [8 n][2 m][16 e]
//     (LDS slot s holds global e-slot (s-nn)&3)
#define WREG 2048
#define SMEM_F 8448        // overlay (reduction scratch) dominates: 33792 B -> 4 blocks/CU

// ---------------- Kernel 1: LayerNorm + QKV projection + mask bit-pack ----------------
__global__ __launch_bounds__(384)
void ln_qkv_kernel(const float* __restrict__ x,
                   const float* __restrict__ Wq, const float* __restrict__ bq,
                   const float* __restrict__ Wk, const float* __restrict__ bk,
                   const float* __restrict__ Wv, const float* __restrict__ bv,
                   const float* __restrict__ gamma, const float* __restrict__ beta,
                   const int* __restrict__ mask,
                   float* __restrict__ qg, float* __restrict__ kg, float* __restrict__ vg,
                   unsigned char* __restrict__ maskb) {
    const int n = blockIdx.x;
    const int t = threadIdx.x;
    __shared__ float hrow[DIM];
    __shared__ float part[4];

    // --- mask bit-pack: row n -> 128 bytes (bit i of byte t = mask[n][t*8+i]) ---
    if (t < 128) {
        const int* mrow = mask + (size_t)n * NNODE + t * 8;
        unsigned pb = 0;
        #pragma unroll
        for (int i = 0; i < 8; ++i) pb |= (mrow[i] ? 1u : 0u) << i;
        maskb[(size_t)n * 128 + t] = (unsigned char)pb;
    }

    float xv = 0.f;
    if (t < 128) {
        xv = x[n * DIM + t];
        float v = xv;
        #pragma unroll
        for (int off = 32; off >= 1; off >>= 1) v += __shfl_xor(v, off);
        if ((t & 63) == 0) part[t >> 6] = v;
    }
    __syncthreads();
    const float mu = (part[0] + part[1]) * (1.0f / DIM);
    const float dx = xv - mu;
    if (t < 128) {
        float v = dx * dx;
        #pragma unroll
        for (int off = 32; off >= 1; off >>= 1) v += __shfl_xor(v, off);
        if ((t & 63) == 0) part[2 + (t >> 6)] = v;
    }
    __syncthreads();
    if (t < 128) {
        const float var = (part[2] + part[3]) * (1.0f / DIM);
        hrow[t] = dx * rsqrtf(var + 1e-5f) * gamma[t] + beta[t];
    }
    __syncthreads();

    const int which = t >> 7;          // 0,1,2 -> q,k,v (wave-uniform)
    const int col = t & 127;
    const float* W = (which == 0) ? Wq : (which == 1) ? Wk : Wv;
    const float* b = (which == 0) ? bq : (which == 1) ? bk : bv;
    float* o       = (which == 0) ? qg : (which == 1) ? kg : vg;
    float a0 = b[col], a1 = 0.f;       // dual accumulators: break 128-deep dep chain
    #pragma unroll 8
    for (int i = 0; i < DIM; i += 2) {
        a0 = fmaf(hrow[i],     W[i * DIM + col],       a0);
        a1 = fmaf(hrow[i + 1], W[(i + 1) * DIM + col], a1);
    }
    o[n * DIM + col] = a0 + a1;
}

// async 16B global->LDS DMA (no VGPR roundtrip, no ds_write).
// offset arg is ALWAYS 0: round-11 lesson — routing chunk lookahead through the
// builtin's offset operand produced NaN (uninitialized-LDS signature; the
// operand's address-side semantics did not match the global-address assumption).
// All lookahead is plain pointer arithmetic on the global pointer.
__device__ __forceinline__ void gll16(const float* g, float* l) {
    auto* gp = (const __attribute__((address_space(1))) unsigned int*)(g);
    auto* lp = (__attribute__((address_space(3))) unsigned int*)(l);
    __builtin_amdgcn_global_load_lds(gp, lp, 16, 0, 0);
}

// ---------------- Kernel 2: wave-private attention, depth-2 ef DMA pipeline ----------------
// grid = 1024 blocks x 256 threads (4 waves), no hot-loop barriers.
// Delivery lessons: r9/r10 (spill: any per-body issue-address math exceeds the
// ~8-VGPR slack over r8's 120), r11 (NaN: builtin offset operand). This round:
// three base pointers advance ONE chunk per body (3 adds, fewer transients than
// r8's per-issue mrow*DIM math); lookahead = kB+256 (kv, 1 ahead), eB+64 (ef,
// 2 ahead) — plain VADDR arithmetic, offset arg 0 (r7/r8-proven semantics).
// ef (64MB L3/HBM stream, ~400-900cyc) gets 4 static buffers, 2 chunks ahead;
// k/v (L2-resident ~200cyc) keep the proven depth-1 double buffer.
// FIFO ledger (m135): steady queue before each wait =
// [ef(c),k(c),v(c),ef(c+1),k(c+1),v(c+1),ef(c+2)] = 7 -> vmcnt(4) drains
// exactly {ef(c),k(c),v(c)}. Tail vmcnt(3), vmcnt(0). First vmcnt(4) also
// flushes prologue const loads (FIFO-oldest, r8-proven).
// Compute body byte-identical to r8. Spill detector: WRITE_SIZE ~8448 KB.
// Lane map: sp = lane>>5 (m parity), np = (lane>>3)&3, h = lane&7;
// lane computes m = 2c+sp x n = np+4*hf (hf=0,1).
__global__ __launch_bounds__(256, 2)
void attn_kernel(const float* __restrict__ qg, const float* __restrict__ kg,
                 const float* __restrict__ vg, const float* __restrict__ ef,
                 const unsigned char* __restrict__ maskb,
                 const float* __restrict__ Wae, const float* __restrict__ bae,
                 float* __restrict__ acc) {
    const int t = threadIdx.x;
    const int lane = t & 63;
    const int wid = t >> 6;
    const int sp = lane >> 5;     // m parity
    const int np = (lane >> 3) & 3;
    const int h  = lane & 7;
    const int bx = blockIdx.x;
    const int n0  = (bx >> 3) * BN;
    const int grp = bx & 7;
    const int mb_w = grp * 128 + wid * 32;   // this wave's private 32 source rows

    __shared__ float smem[SMEM_F];
    float* wreg = smem + wid * WREG;         // kv at +0/+512; ef at +1024 + b*256

    // --- per-thread constants (global, L2-hot) ---
    float qreg[2][DK];
    #pragma unroll
    for (int hf = 0; hf < 2; ++hf) {
        const float* qp = qg + (size_t)(n0 + np + 4 * hf) * DIM + h * DK;
        #pragma unroll
        for (int d4 = 0; d4 < 4; ++d4) {
            const float4 qv = *(const float4*)(qp + d4 * 4);
            qreg[hf][d4 * 4 + 0] = qv.x; qreg[hf][d4 * 4 + 1] = qv.y;
            qreg[hf][d4 * 4 + 2] = qv.z; qreg[hf][d4 * 4 + 3] = qv.w;
        }
    }
    float waec[EDIM];
    #pragma unroll
    for (int e = 0; e < EDIM; ++e) waec[e] = Wae[e * HEADS + h] * LOG2E;
    const float baeh = bae[h] * LOG2E;

    // mask bits for this wave's 32 m: u32 per hf; bit (2c+sp) via running >>2
    unsigned mk0 = *(const unsigned*)(maskb + (size_t)(n0 + np)     * 128 + (mb_w >> 3)) >> sp;
    unsigned mk1 = *(const unsigned*)(maskb + (size_t)(n0 + np + 4) * 128 + (mb_w >> 3)) >> sp;

    float sl[2] = {0.f, 0.f};
    float accv[2][DK], accT[2][EDIM];
    #pragma unroll
    for (int hf = 0; hf < 2; ++hf) {
        #pragma unroll
        for (int d = 0; d < DK; ++d) accv[hf][d] = 0.f;
        #pragma unroll
        for (int e = 0; e < EDIM; ++e) accT[hf][e] = 0.f;
    }

    // --- DMA base pointers, ONE per operand, advancing one chunk per body
    //     (lane-swizzled source so linear LDS dst realizes the swizzled layout) ---
    const int s0   = lane & 3;
    const int h0   = (lane >> 2) & 7;
    const int row0 = lane >> 5;                       // k/v: 2 rows per inst
    const int koffl = row0 * 128 + h0 * 16 + (((s0 - (h0 >> 1)) & 3) << 2);
    const int nn0 = lane >> 3;                        // ef: 8n x 2m x 16e, one inst
    const int mm0 = (lane >> 2) & 1;
    const int eoffl = nn0 * (NNODE * EDIM) + mm0 * EDIM + (((s0 - nn0) & 3) << 2);
    const float* kB = kg + (size_t)mb_w * DIM + koffl;
    const float* vB = vg + (size_t)mb_w * DIM + koffl;
    const float* eB = ef + (size_t)n0 * NNODE * EDIM + (size_t)mb_w * EDIM + eoffl;

    // --- read-side rotated sub-slot offsets (static-indexed, 4+4 regs) ---
    int krot[4], erot[4];
    const int rotk = (h >> 1) & 3;
    #pragma unroll
    for (int i = 0; i < 4; ++i) {
        krot[i] = ((i + rotk) & 3) << 2;
        erot[i] = ((i + np) & 3) << 2;
    }

#define KVB(p) (wreg + (p) * 512)
#define EFBUF(b) (wreg + 1024 + (b) * 256)

#define COMPUTE_CHUNK(KV, EB)                                                  \
    do {                                                                       \
        const float* kl = (KV) + sp * 128 + h * 16;                            \
        const float* vl = kl + 256;                                            \
        const float* eb = (EB) + np * 32 + sp * 16;                            \
        float kk[DK], vv[DK];                                                  \
        _Pragma("unroll")                                                      \
        for (int i = 0; i < 4; ++i) {                                          \
            const float4 k4 = *(const float4*)(kl + krot[i]);                  \
            kk[i*4+0]=k4.x; kk[i*4+1]=k4.y; kk[i*4+2]=k4.z; kk[i*4+3]=k4.w;    \
            const float4 v4 = *(const float4*)(vl + krot[i]);                  \
            vv[i*4+0]=v4.x; vv[i*4+1]=v4.y; vv[i*4+2]=v4.z; vv[i*4+3]=v4.w;    \
        }                                                                      \
        _Pragma("unroll")                                                      \
        for (int hf = 0; hf < 2; ++hf) {                                       \
            float efv[EDIM];                                                   \
            _Pragma("unroll")                                                  \
            for (int i = 0; i < 4; ++i) {                                      \
                const float4 e4 = *(const float4*)(eb + hf * 128 + erot[i]);   \
                efv[i*4+0]=e4.x; efv[i*4+1]=e4.y;                              \
                efv[i*4+2]=e4.z; efv[i*4+3]=e4.w;                              \
            }                                                                  \
            float bias = baeh, dot = 0.f;                                      \
            _Pragma("unroll")                                                  \
            for (int e = 0; e < EDIM; ++e) bias = fmaf(efv[e], waec[e], bias); \
            _Pragma("unroll")                                                  \
            for (int d = 0; d < DK; ++d) dot = fmaf(qreg[hf][d], kk[d], dot);  \
            const float lg = fmaf(dot, 0.25f * LOG2E, bias);                   \
            const unsigned mv = (hf ? mk1 : mk0) & 1u;                         \
            const float p = mv ? __builtin_amdgcn_exp2f(lg) : 0.f;             \
            sl[hf] += p;                                                       \
            _Pragma("unroll")                                                  \
            for (int d = 0; d < DK; ++d) accv[hf][d] = fmaf(p, vv[d], accv[hf][d]); \
            _Pragma("unroll")                                                  \
            for (int e = 0; e < EDIM; ++e) accT[hf][e] = fmaf(p, efv[e], accT[hf][e]); \
        }                                                                      \
        mk0 >>= 2; mk1 >>= 2;                                                  \
    } while (0)

    // prologue: FIFO pattern [ef(0), k(0), v(0), ef(1)]
    gll16(eB, EFBUF(0));
    gll16(kB, KVB(0)); gll16(vB, KVB(0) + 256);
    gll16(eB + 32, EFBUF(1));

    // main loop: chunks 0..11 as 3 groups x 4 static bodies. Body for chunk c
    // (pointers at c): issue kv(c+1) at +256, ef(c+2) at +64; vmcnt(4);
    // compute kv[c&1], ef[c&3]; advance pointers one chunk.
    #pragma unroll 1
    for (int g = 0; g < 3; ++g) {
        #pragma unroll
        for (int i = 0; i < 4; ++i) {
            float* kvN = KVB((i + 1) & 1);
            gll16(kB + 256, kvN); gll16(vB + 256, kvN + 256);
            gll16(eB + 64, EFBUF((i + 2) & 3));
            asm volatile("s_waitcnt vmcnt(4)" ::: "memory");
            COMPUTE_CHUNK(KVB(i & 1), EFBUF(i & 3));
            kB += 256; vB += 256; eB += 32;
        }
    }
    // epilogue: chunks 12..15 (pointers at 12; no issues past chunk 15)
    gll16(kB + 256, KVB(1)); gll16(vB + 256, KVB(1) + 256);
    gll16(eB + 64, EFBUF(2));
    asm volatile("s_waitcnt vmcnt(4)" ::: "memory");
    COMPUTE_CHUNK(KVB(0), EFBUF(0));                 // chunk 12
    kB += 256; vB += 256; eB += 32;
    gll16(kB + 256, KVB(0)); gll16(vB + 256, KVB(0) + 256);
    gll16(eB + 64, EFBUF(3));
    asm volatile("s_waitcnt vmcnt(4)" ::: "memory");
    COMPUTE_CHUNK(KVB(1), EFBUF(1));                 // chunk 13
    kB += 256; vB += 256;
    gll16(kB + 256, KVB(1)); gll16(vB + 256, KVB(1) + 256);
    asm volatile("s_waitcnt vmcnt(3)" ::: "memory");
    COMPUTE_CHUNK(KVB(0), EFBUF(2));                 // chunk 14
    asm volatile("s_waitcnt vmcnt(0)" ::: "memory");
    COMPUTE_CHUNK(KVB(1), EFBUF(3));                 // chunk 15
#undef COMPUTE_CHUNK
#undef KVB
#undef EFBUF

    // --- reduce sp-pairs within wave (lane ^ 32): combines the two m-parities ---
    #pragma unroll
    for (int hf = 0; hf < 2; ++hf) {
        sl[hf] += __shfl_xor(sl[hf], 32);
        #pragma unroll
        for (int d = 0; d < DK; ++d) accv[hf][d] += __shfl_xor(accv[hf][d], 32);
        #pragma unroll
        for (int e = 0; e < EDIM; ++e) accT[hf][e] += __shfl_xor(accT[hf][e], 32);
    }
    __syncthreads();                 // all waves done with private regions -> overlay
    float* red = smem;               // [w4][np4][h8][hf2][33] = 8448 f32 overlay
    if (lane < 32) {
        float* rp = &red[((wid * 4 + np) * 8 + h) * 66];
        #pragma unroll
        for (int hf = 0; hf < 2; ++hf) {
            rp[hf * 33 + 0] = sl[hf];
            #pragma unroll
            for (int d = 0; d < DK; ++d) rp[hf * 33 + 1 + d] = accv[hf][d];
            #pragma unroll
            for (int e = 0; e < EDIM; ++e) rp[hf * 33 + 17 + e] = accT[hf][e];
        }
    }
    __syncthreads();
    // --- combine 4 wave copies, plain store to this block's group slot ---
    for (int v = t; v < BN * HEADS * 33; v += 256) {   // 2112 values
        const int n = v / 264;
        const int rem = v - n * 264;
        const int hh = rem / 33;
        const int idx = rem - hh * 33;
        const int nnp = n & 3, hf = n >> 2;
        float sum = 0.f;
        #pragma unroll
        for (int w = 0; w < 4; ++w)
            sum += red[((w * 4 + nnp) * 8 + hh) * 66 + hf * 33 + idx];
        acc[((size_t)(n0 + n) * NGRP + grp) * 264 + rem] = sum;
    }
}

// ---------------- Kernel 3: epilogue (sum groups, Wve, normalize, Wo, residual) ----------------
__global__ __launch_bounds__(128)
void final_kernel(const float* __restrict__ acc,
                  const float* __restrict__ Wve, const float* __restrict__ bve,
                  const float* __restrict__ x,
                  const float* __restrict__ Wo, const float* __restrict__ bo,
                  float* __restrict__ out) {
    const int n = blockIdx.x, t = threadIdx.x;
    __shared__ float ab[HEADS * 33];
    __shared__ float orow[DIM];
    const float* ap = acc + (size_t)n * NGRP * 264;
    for (int u = t; u < HEADS * 33; u += 128) {
        float sv = 0.f;
        #pragma unroll
        for (int g = 0; g < NGRP; ++g) sv += ap[g * 264 + u];
        ab[u] = sv;
    }
    __syncthreads();
    const int col = t, hh = col >> 4, dd = col & 15;
    const float slv = ab[hh * 33];
    float acc2 = 0.f;
    #pragma unroll
    for (int e = 0; e < EDIM; ++e) acc2 = fmaf(ab[hh * 33 + 17 + e], Wve[e * DIM + col], acc2);
    orow[col] = (ab[hh * 33 + 1 + dd] + acc2) / slv + bve[col];
    __syncthreads();
    float o0 = bo[col] + x[(size_t)n * DIM + col], o1 = 0.f;
    #pragma unroll 8
    for (int i = 0; i < DIM; i += 2) {
        o0 = fmaf(orow[i],     Wo[i * DIM + col],       o0);
        o1 = fmaf(orow[i + 1], Wo[(i + 1) * DIM + col], o1);
    }
    out[(size_t)n * DIM + col] = o0 + o1;
}

extern "C" void kernel_launch(void* const* d_in, const int* in_sizes, int n_in,
                              void* d_out, int out_size, void* d_ws, size_t ws_size,
                              hipStream_t stream) {
    const float* x     = (const float*)d_in[0];
    const float* ef    = (const float*)d_in[1];
    const int*   mask  = (const int*)d_in[2];
    const float* Wq    = (const float*)d_in[3];
    const float* bq    = (const float*)d_in[4];
    const float* Wk    = (const float*)d_in[5];
    const float* bk    = (const float*)d_in[6];
    const float* Wv    = (const float*)d_in[7];
    const float* bv    = (const float*)d_in[8];
    const float* Wae   = (const float*)d_in[9];
    const float* bae   = (const float*)d_in[10];
    const float* Wve   = (const float*)d_in[11];
    const float* bve   = (const float*)d_in[12];
    const float* Wo    = (const float*)d_in[13];
    const float* bo    = (const float*)d_in[14];
    const float* gamma = (const float*)d_in[15];
    const float* beta  = (const float*)d_in[16];

    float* ws = (float*)d_ws;
    float* accb = ws;                                   // 1024*8*264 f32
    float* qg   = ws + (size_t)NNODE * NGRP * 264;
    float* kg   = qg + (size_t)NNODE * DIM;
    float* vg   = kg + (size_t)NNODE * DIM;
    unsigned char* maskb = (unsigned char*)(vg + (size_t)NNODE * DIM);  // 128 KB

    ln_qkv_kernel<<<NNODE, 384, 0, stream>>>(x, Wq, bq, Wk, bk, Wv, bv, gamma, beta,
                                             mask, qg, kg, vg, maskb);
    attn_kernel<<<(NNODE / BN) * NGRP, 256, 0, stream>>>(qg, kg, vg, ef, maskb, Wae, bae, accb);
    final_kernel<<<NNODE, 128, 0, stream>>>(accb, Wve, bve, x, Wo, bo, (float*)d_out);
}

// Round 13
// 163.693 us; speedup vs baseline: 1.7551x; 1.7551x over previous
//
#include <hip/hip_runtime.h>
#include <hip/hip_bf16.h>

#define NNODE 1024
#define DIM 128
#define HEADS 8
#define DK 16
#define EDIM 16
#define BN 8               // target nodes per attn block
#define NGRP 8             // m-group blocks per target row (128 rows each)
#define LOG2E 1.44269504f

// per-WAVE region (dwords), double-buffered, UNPADDED (global_load_lds writes
// linearly; conflict-freedom via source-swizzle + rotated read, verified r7/r8:
// bank conflicts 1.83M -> 254K):
//   parity p at wid*WREG + p*PAR:
//     k  [2 rows][128]  at +0    (LDS slot s holds global d-slot (s-(h>>1))&3)
//     v  [2 rows][128]  at +256
//     ef [8 n][2 m][16] at +512  (LDS slot s holds global e-slot (s-nn)&3)
#define PAR 768
#define WREG (2 * PAR)
#define SMEM_F 8448        // overlay (reduction scratch) dominates: 33792 B -> 4 blocks/CU

// ---------------- Kernel 1: LayerNorm + QKV projection + mask bit-pack ----------------
__global__ __launch_bounds__(384)
void ln_qkv_kernel(const float* __restrict__ x,
                   const float* __restrict__ Wq, const float* __restrict__ bq,
                   const float* __restrict__ Wk, const float* __restrict__ bk,
                   const float* __restrict__ Wv, const float* __restrict__ bv,
                   const float* __restrict__ gamma, const float* __restrict__ beta,
                   const int* __restrict__ mask,
                   float* __restrict__ qg, float* __restrict__ kg, float* __restrict__ vg,
                   unsigned char* __restrict__ maskb) {
    const int n = blockIdx.x;
    const int t = threadIdx.x;
    __shared__ float hrow[DIM];
    __shared__ float part[4];

    // --- mask bit-pack: row n -> 128 bytes (bit i of byte t = mask[n][t*8+i]) ---
    if (t < 128) {
        const int* mrow = mask + (size_t)n * NNODE + t * 8;
        unsigned pb = 0;
        #pragma unroll
        for (int i = 0; i < 8; ++i) pb |= (mrow[i] ? 1u : 0u) << i;
        maskb[(size_t)n * 128 + t] = (unsigned char)pb;
    }

    float xv = 0.f;
    if (t < 128) {
        xv = x[n * DIM + t];
        float v = xv;
        #pragma unroll
        for (int off = 32; off >= 1; off >>= 1) v += __shfl_xor(v, off);
        if ((t & 63) == 0) part[t >> 6] = v;
    }
    __syncthreads();
    const float mu = (part[0] + part[1]) * (1.0f / DIM);
    const float dx = xv - mu;
    if (t < 128) {
        float v = dx * dx;
        #pragma unroll
        for (int off = 32; off >= 1; off >>= 1) v += __shfl_xor(v, off);
        if ((t & 63) == 0) part[2 + (t >> 6)] = v;
    }
    __syncthreads();
    if (t < 128) {
        const float var = (part[2] + part[3]) * (1.0f / DIM);
        hrow[t] = dx * rsqrtf(var + 1e-5f) * gamma[t] + beta[t];
    }
    __syncthreads();

    const int which = t >> 7;          // 0,1,2 -> q,k,v (wave-uniform)
    const int col = t & 127;
    const float* W = (which == 0) ? Wq : (which == 1) ? Wk : Wv;
    const float* b = (which == 0) ? bq : (which == 1) ? bk : bv;
    float* o       = (which == 0) ? qg : (which == 1) ? kg : vg;
    float a0 = b[col], a1 = 0.f;       // dual accumulators: break 128-deep dep chain
    #pragma unroll 8
    for (int i = 0; i < DIM; i += 2) {
        a0 = fmaf(hrow[i],     W[i * DIM + col],       a0);
        a1 = fmaf(hrow[i + 1], W[(i + 1) * DIM + col], a1);
    }
    o[n * DIM + col] = a0 + a1;
}

// async 16B global->LDS DMA (no VGPR roundtrip, no ds_write; offset arg always
// 0 — r11 lesson: the builtin's offset operand broke correctness)
__device__ __forceinline__ void gll16(const float* g, float* l) {
    auto* gp = (const __attribute__((address_space(1))) unsigned int*)(g);
    auto* lp = (__attribute__((address_space(3))) unsigned int*)(l);
    __builtin_amdgcn_global_load_lds(gp, lp, 16, 0, 0);
}

// ---------------- Kernel 2: wave-private attention, DMA-staged (r8) + setprio ----------------
// EXACT r8 structure (best verified: attn 47us, VGPR 120, zero spill) plus ONE
// register-free addition: s_setprio(1) around the compute phase (T5). Mechanism
// requires phase-diverse waves (m191 attn +4-7%; m190 lockstep GEMM null) —
// r8's barrier-free wave-private loop is that regime: 16 free-running waves/CU,
// some DMA-waiting, some computing; priority lets compute-phase waves win issue.
// Closed branch (r9-r12, 4 failed attempts): ef depth-2 prefetch cannot be
// expressed within the ~8-VGPR slack over r8's 120 — every variant spilled
// (WRITE 213-486 MB) or broke semantics. Spill detector: WRITE_SIZE ~8448 KB.
// grid = 1024 blocks x 256 threads (4 waves), no hot-loop barriers.
// chunk = 2 m-rows (16 chunks); batch = 3 DMA (k,v,ef one inst each);
// vmcnt(3) steady (first one also flushes const loads, FIFO-oldest m135),
// vmcnt(0) only at tail. Mask bit-packed in 2 u32 regs (bit (2c+sp), >>2/chunk).
// launch_bounds (256,2): VGPR clamp 128; LDS arena = reduction overlay 33792 B
// -> 4 blocks/CU.
// Lane map: sp = lane>>5 (m parity), np = (lane>>3)&3, h = lane&7;
// lane computes m = 2c+sp x n = np+4*hf (hf=0,1).
__global__ __launch_bounds__(256, 2)
void attn_kernel(const float* __restrict__ qg, const float* __restrict__ kg,
                 const float* __restrict__ vg, const float* __restrict__ ef,
                 const unsigned char* __restrict__ maskb,
                 const float* __restrict__ Wae, const float* __restrict__ bae,
                 float* __restrict__ acc) {
    const int t = threadIdx.x;
    const int lane = t & 63;
    const int wid = t >> 6;
    const int sp = lane >> 5;     // m parity
    const int np = (lane >> 3) & 3;
    const int h  = lane & 7;
    const int bx = blockIdx.x;
    const int n0  = (bx >> 3) * BN;
    const int grp = bx & 7;
    const int mb_w = grp * 128 + wid * 32;   // this wave's private 32 source rows

    __shared__ float smem[SMEM_F];
    float* wreg = smem + wid * WREG;         // wave-uniform base; b0=+0, b1=+PAR

    // --- per-thread constants (global, L2-hot) ---
    float qreg[2][DK];
    #pragma unroll
    for (int hf = 0; hf < 2; ++hf) {
        const float* qp = qg + (size_t)(n0 + np + 4 * hf) * DIM + h * DK;
        #pragma unroll
        for (int d4 = 0; d4 < 4; ++d4) {
            const float4 qv = *(const float4*)(qp + d4 * 4);
            qreg[hf][d4 * 4 + 0] = qv.x; qreg[hf][d4 * 4 + 1] = qv.y;
            qreg[hf][d4 * 4 + 2] = qv.z; qreg[hf][d4 * 4 + 3] = qv.w;
        }
    }
    float waec[EDIM];
    #pragma unroll
    for (int e = 0; e < EDIM; ++e) waec[e] = Wae[e * HEADS + h] * LOG2E;
    const float baeh = bae[h] * LOG2E;

    // mask bits for this wave's 32 m: u32 per hf; bit (2c+sp) via running >>2
    unsigned mk0 = *(const unsigned*)(maskb + (size_t)(n0 + np)     * 128 + (mb_w >> 3)) >> sp;
    unsigned mk1 = *(const unsigned*)(maskb + (size_t)(n0 + np + 4) * 128 + (mb_w >> 3)) >> sp;

    float sl[2] = {0.f, 0.f};
    float accv[2][DK], accT[2][EDIM];
    #pragma unroll
    for (int hf = 0; hf < 2; ++hf) {
        #pragma unroll
        for (int d = 0; d < DK; ++d) accv[hf][d] = 0.f;
        #pragma unroll
        for (int e = 0; e < EDIM; ++e) accT[hf][e] = 0.f;
    }

    // --- DMA per-lane source offsets (swizzled so linear LDS dst = swizzled layout) ---
    const int s0   = lane & 3;
    const int h0   = (lane >> 2) & 7;
    const int row0 = lane >> 5;                       // k/v: 2 rows per inst
    const int koffl = row0 * 128 + h0 * 16 + (((s0 - (h0 >> 1)) & 3) << 2);
    const int nn0 = lane >> 3;                        // ef: 8n x 2m x 16e, one inst
    const int mm0 = (lane >> 2) & 1;
    const int eoffl = nn0 * (NNODE * EDIM) + mm0 * EDIM + (((s0 - nn0) & 3) << 2);
    const float* efb = ef + (size_t)n0 * NNODE * EDIM;

    // --- read-side rotated sub-slot offsets (static-indexed, 4+4 regs) ---
    int krot[4], erot[4];
    const int rotk = (h >> 1) & 3;
    #pragma unroll
    for (int i = 0; i < 4; ++i) {
        krot[i] = ((i + rotk) & 3) << 2;
        erot[i] = ((i + np) & 3) << 2;
    }

#define ISSUE_BATCH(DB, MB)                                              \
    do {                                                                 \
        float* db = (DB);                                                \
        gll16(kg + (size_t)(MB) * DIM + koffl, db);                      \
        gll16(vg + (size_t)(MB) * DIM + koffl, db + 256);                \
        gll16(efb + (size_t)(MB) * EDIM + eoffl, db + 512);              \
    } while (0)

#define COMPUTE_CHUNK(DB)                                                      \
    do {                                                                       \
        __builtin_amdgcn_s_setprio(1);                                         \
        const float* kl = (DB) + sp * 128 + h * 16;                            \
        const float* vl = kl + 256;                                            \
        const float* eb = (DB) + 512 + np * 32 + sp * 16;                      \
        float kk[DK], vv[DK];                                                  \
        _Pragma("unroll")                                                      \
        for (int i = 0; i < 4; ++i) {                                          \
            const float4 k4 = *(const float4*)(kl + krot[i]);                  \
            kk[i*4+0]=k4.x; kk[i*4+1]=k4.y; kk[i*4+2]=k4.z; kk[i*4+3]=k4.w;    \
            const float4 v4 = *(const float4*)(vl + krot[i]);                  \
            vv[i*4+0]=v4.x; vv[i*4+1]=v4.y; vv[i*4+2]=v4.z; vv[i*4+3]=v4.w;    \
        }                                                                      \
        _Pragma("unroll")                                                      \
        for (int hf = 0; hf < 2; ++hf) {                                       \
            float efv[EDIM];                                                   \
            _Pragma("unroll")                                                  \
            for (int i = 0; i < 4; ++i) {                                      \
                const float4 e4 = *(const float4*)(eb + hf * 128 + erot[i]);   \
                efv[i*4+0]=e4.x; efv[i*4+1]=e4.y;                              \
                efv[i*4+2]=e4.z; efv[i*4+3]=e4.w;                              \
            }                                                                  \
            float bias = baeh, dot = 0.f;                                      \
            _Pragma("unroll")                                                  \
            for (int e = 0; e < EDIM; ++e) bias = fmaf(efv[e], waec[e], bias); \
            _Pragma("unroll")                                                  \
            for (int d = 0; d < DK; ++d) dot = fmaf(qreg[hf][d], kk[d], dot);  \
            const float lg = fmaf(dot, 0.25f * LOG2E, bias);                   \
            const unsigned mv = (hf ? mk1 : mk0) & 1u;                         \
            const float p = mv ? __builtin_amdgcn_exp2f(lg) : 0.f;             \
            sl[hf] += p;                                                       \
            _Pragma("unroll")                                                  \
            for (int d = 0; d < DK; ++d) accv[hf][d] = fmaf(p, vv[d], accv[hf][d]); \
            _Pragma("unroll")                                                  \
            for (int e = 0; e < EDIM; ++e) accT[hf][e] = fmaf(p, efv[e], accT[hf][e]); \
        }                                                                      \
        mk0 >>= 2; mk1 >>= 2;                                                  \
        __builtin_amdgcn_s_setprio(0);                                         \
    } while (0)

    // prologue: batch for chunk 0 (3 DMA outstanding + const loads above)
    ISSUE_BATCH(wreg, mb_w);

    // 2x-unrolled main loop over 16 chunks of 2 m-rows.
    // Ledger: first vmcnt(3) drains chunk-0 batch AND all prologue const loads
    // (FIFO-oldest, m135). Steady state: issue next batch (+3 -> 6), vmcnt(3)
    // drains current chunk's 3. Tail: vmcnt(0).
    #pragma unroll 1
    for (int cc = 0; cc < 16; cc += 2) {
        ISSUE_BATCH(wreg + PAR, mb_w + 2 * (cc + 1));
        asm volatile("s_waitcnt vmcnt(3)" ::: "memory");
        COMPUTE_CHUNK(wreg);
        if (cc < 14) {
            ISSUE_BATCH(wreg, mb_w + 2 * (cc + 2));
            asm volatile("s_waitcnt vmcnt(3)" ::: "memory");
        } else {
            asm volatile("s_waitcnt vmcnt(0)" ::: "memory");
        }
        COMPUTE_CHUNK(wreg + PAR);
    }
#undef ISSUE_BATCH
#undef COMPUTE_CHUNK

    // --- reduce sp-pairs within wave (lane ^ 32): combines the two m-parities ---
    #pragma unroll
    for (int hf = 0; hf < 2; ++hf) {
        sl[hf] += __shfl_xor(sl[hf], 32);
        #pragma unroll
        for (int d = 0; d < DK; ++d) accv[hf][d] += __shfl_xor(accv[hf][d], 32);
        #pragma unroll
        for (int e = 0; e < EDIM; ++e) accT[hf][e] += __shfl_xor(accT[hf][e], 32);
    }
    __syncthreads();                 // all waves done with private regions -> overlay
    float* red = smem;               // [w4][np4][h8][hf2][33] = 8448 f32 overlay
    if (lane < 32) {
        float* rp = &red[((wid * 4 + np) * 8 + h) * 66];
        #pragma unroll
        for (int hf = 0; hf < 2; ++hf) {
            rp[hf * 33 + 0] = sl[hf];
            #pragma unroll
            for (int d = 0; d < DK; ++d) rp[hf * 33 + 1 + d] = accv[hf][d];
            #pragma unroll
            for (int e = 0; e < EDIM; ++e) rp[hf * 33 + 17 + e] = accT[hf][e];
        }
    }
    __syncthreads();
    // --- combine 4 wave copies, plain store to this block's group slot ---
    for (int v = t; v < BN * HEADS * 33; v += 256) {   // 2112 values
        const int n = v / 264;
        const int rem = v - n * 264;
        const int hh = rem / 33;
        const int idx = rem - hh * 33;
        const int nnp = n & 3, hf = n >> 2;
        float sum = 0.f;
        #pragma unroll
        for (int w = 0; w < 4; ++w)
            sum += red[((w * 4 + nnp) * 8 + hh) * 66 + hf * 33 + idx];
        acc[((size_t)(n0 + n) * NGRP + grp) * 264 + rem] = sum;
    }
}

// ---------------- Kernel 3: epilogue (sum groups, Wve, normalize, Wo, residual) ----------------
__global__ __launch_bounds__(128)
void final_kernel(const float* __restrict__ acc,
                  const float* __restrict__ Wve, const float* __restrict__ bve,
                  const float* __restrict__ x,
                  const float* __restrict__ Wo, const float* __restrict__ bo,
                  float* __restrict__ out) {
    const int n = blockIdx.x, t = threadIdx.x;
    __shared__ float ab[HEADS * 33];
    __shared__ float orow[DIM];
    const float* ap = acc + (size_t)n * NGRP * 264;
    for (int u = t; u < HEADS * 33; u += 128) {
        float sv = 0.f;
        #pragma unroll
        for (int g = 0; g < NGRP; ++g) sv += ap[g * 264 + u];
        ab[u] = sv;
    }
    __syncthreads();
    const int col = t, hh = col >> 4, dd = col & 15;
    const float slv = ab[hh * 33];
    float acc2 = 0.f;
    #pragma unroll
    for (int e = 0; e < EDIM; ++e) acc2 = fmaf(ab[hh * 33 + 17 + e], Wve[e * DIM + col], acc2);
    orow[col] = (ab[hh * 33 + 1 + dd] + acc2) / slv + bve[col];
    __syncthreads();
    float o0 = bo[col] + x[(size_t)n * DIM + col], o1 = 0.f;
    #pragma unroll 8
    for (int i = 0; i < DIM; i += 2) {
        o0 = fmaf(orow[i],     Wo[i * DIM + col],       o0);
        o1 = fmaf(orow[i + 1], Wo[(i + 1) * DIM + col], o1);
    }
    out[(size_t)n * DIM + col] = o0 + o1;
}

extern "C" void kernel_launch(void* const* d_in, const int* in_sizes, int n_in,
                              void* d_out, int out_size, void* d_ws, size_t ws_size,
                              hipStream_t stream) {
    const float* x     = (const float*)d_in[0];
    const float* ef    = (const float*)d_in[1];
    const int*   mask  = (const int*)d_in[2];
    const float* Wq    = (const float*)d_in[3];
    const float* bq    = (const float*)d_in[4];
    const float* Wk    = (const float*)d_in[5];
    const float* bk    = (const float*)d_in[6];
    const float* Wv    = (const float*)d_in[7];
    const float* bv    = (const float*)d_in[8];
    const float* Wae   = (const float*)d_in[9];
    const float* bae   = (const float*)d_in[10];
    const float* Wve   = (const float*)d_in[11];
    const float* bve   = (const float*)d_in[12];
    const float* Wo    = (const float*)d_in[13];
    const float* bo    = (const float*)d_in[14];
    const float* gamma = (const float*)d_in[15];
    const float* beta  = (const float*)d_in[16];

    float* ws = (float*)d_ws;
    float* accb = ws;                                   // 1024*8*264 f32
    float* qg   = ws + (size_t)NNODE * NGRP * 264;
    float* kg   = qg + (size_t)NNODE * DIM;
    float* vg   = kg + (size_t)NNODE * DIM;
    unsigned char* maskb = (unsigned char*)(vg + (size_t)NNODE * DIM);  // 128 KB

    ln_qkv_kernel<<<NNODE, 384, 0, stream>>>(x, Wq, bq, Wk, bk, Wv, bv, gamma, beta,
                                             mask, qg, kg, vg, maskb);
    attn_kernel<<<(NNODE / BN) * NGRP, 256, 0, stream>>>(qg, kg, vg, ef, maskb, Wae, bae, accb);
    final_kernel<<<NNODE, 128, 0, stream>>>(accb, Wve, bve, x, Wo, bo, (float*)d_out);
}